// Round 6
// baseline (136.846 us; speedup 1.0000x reference)
//
#include <hip/hip_runtime.h>
#include <hip/hip_bf16.h>
#include <math.h>

typedef unsigned short u16;

// ---- ws layout (float offsets), fb = staging floats ----
// [0, fb)            : X2 then Y staging (mf32: float; else u16 bf16)
// fb+0    .. +1024   : s2[b][h] (ba0 folded)
// fb+1024 .. +1152   : w2
// fb+1152 .. +1280   : -0.99*w2
// fb+1280 .. +1288   : V fp32
// fb+1288 .. +1800   : hn fp32
// fb+1800 .. +2312   : cn fp32
// fb+2313            : ba2 fp32

__device__ __forceinline__ u16 f2b(float x) { __hip_bfloat16 b = __float2bfloat16(x); return *(u16*)&b; }
__device__ __forceinline__ void cvt8(const uint4 u, float* f) {
    f[0] = __uint_as_float(u.x << 16); f[1] = __uint_as_float(u.x & 0xFFFF0000u);
    f[2] = __uint_as_float(u.y << 16); f[3] = __uint_as_float(u.y & 0xFFFF0000u);
    f[4] = __uint_as_float(u.z << 16); f[5] = __uint_as_float(u.z & 0xFFFF0000u);
    f[6] = __uint_as_float(u.w << 16); f[7] = __uint_as_float(u.w & 0xFFFF0000u);
}

// ============================================================================
// K1: mean -> LSTM -> V head -> s2/w2/ba2 tables. grid(8), block(256). fp32 in.
// ============================================================================
__global__ __launch_bounds__(256) void k1_head(
    const float* __restrict__ ope, const float* __restrict__ hin, const float* __restrict__ cin,
    const float* __restrict__ W_ih, const float* __restrict__ W_hh,
    const float* __restrict__ b_ih, const float* __restrict__ b_hh,
    const float* __restrict__ Wv0, const float* __restrict__ bv0,
    const float* __restrict__ Wv1, const float* __restrict__ bv1,
    const float* __restrict__ Wv2, const float* __restrict__ bv2,
    const float* __restrict__ Wa0, const float* __restrict__ ba0,
    const float* __restrict__ Wa2, const float* __restrict__ ba2,
    float* __restrict__ ws, int fb)
{
    const int b = blockIdx.x, t = threadIdx.x;
    __shared__ float red[256], state[64], hvec[64], gl[256], hn_s[64], t0a[128], t1a[128];

    // state = mean over rows 1..256 of ope_gat[b] (258 rows, slice [1:-1])
    {
        const int d = t & 63, q = t >> 6;
        const float* p = ope + b * 16512 + (1 + q * 64) * 64 + d;
        float s = 0.f;
        #pragma unroll 8
        for (int r = 0; r < 64; ++r) s += p[r * 64];
        red[t] = s;
    }
    __syncthreads();
    if (t < 64)       state[t]   = (red[t] + red[t+64] + red[t+128] + red[t+192]) * (1.f/256.f);
    else if (t < 128) hvec[t-64] = hin[b*64 + (t-64)];
    __syncthreads();

    // gates = state @ W_ih.T + b_ih + h @ W_hh.T + b_hh
    {
        float g = b_ih[t] + b_hh[t];
        #pragma unroll 8
        for (int d = 0; d < 64; ++d)
            g += state[d] * W_ih[t*64 + d] + hvec[d] * W_hh[t*64 + d];
        gl[t] = g;
    }
    __syncthreads();

    // LSTM cell, split order i,f,g,o
    if (t < 64) {
        const float ig = gl[t], fg = gl[64+t], gg = gl[128+t], og = gl[192+t];
        const float c  = cin[b*64 + t];
        const float si = 1.f/(1.f + expf(-ig));
        const float sf = 1.f/(1.f + expf(-fg));
        const float so = 1.f/(1.f + expf(-og));
        const float cn = sf*c + si*tanhf(gg);
        const float hn = so*tanhf(cn);
        ws[fb + 1288 + b*64 + t] = hn;
        ws[fb + 1800 + b*64 + t] = cn;
        hn_s[t] = hn;
    }
    __syncthreads();

    // V layer 0 (no activation per reference): t0a = hn @ Wv0.T + bv0
    if (t < 128) {
        float a = bv0[t];
        #pragma unroll 8
        for (int d = 0; d < 64; ++d) a += hn_s[d] * Wv0[t*64 + d];
        t0a[t] = a;
    }
    __syncthreads();
    if (t < 128) {
        float a = bv1[t];
        #pragma unroll 8
        for (int d = 0; d < 128; ++d) a += t0a[d] * Wv1[t*128 + d];
        a = (a >= 0.f) ? a : 0.01f*a;
        t1a[t] = a * Wv2[t];
        float s2 = ba0[t];
        #pragma unroll 8
        for (int d = 0; d < 64; ++d) s2 += hn_s[d] * Wa0[t*192 + d];
        ws[fb + b*128 + t] = s2;
        const float w2v = Wa2[t];
        ws[fb + 1024 + t] = w2v;
        ws[fb + 1152 + t] = -0.99f * w2v;
    }
    __syncthreads();
    if (t == 0) {
        float v = bv2[0];
        for (int g = 0; g < 128; ++g) v += t1a[g];
        ws[fb + 1280 + b] = v;
        ws[fb + 2313]    = ba2[0];
    }
}

// ============================================================================
// K2: X2[b][o][g] and Y[b][i][g]. grid(8*32=256), block(256).
// rows 0..255 = o-side (ope, Wo, +s2, +ba1 folded), 256..511 = i-side (ins, Wi)
// ============================================================================
template<bool MF32>
__device__ void k2_body(const float* ope, const float* ins, const float* Wa0,
    const float* Wa1, const float* ba1, float* ws, int fb,
    u16* Wa1s, u16* Wsel, u16* inrows, float* P)
{
    const int t = threadIdx.x;
    const int b = blockIdx.x >> 5;
    const int r0 = (blockIdx.x & 31) * 16;
    const int side = (r0 >= 256) ? 1 : 0;

    // stage Wa1 -> LDS bf16 [128][136]
    #pragma unroll
    for (int k = 0; k < 16; ++k) {
        const int e4 = t + k*256;
        const int g = e4 >> 5, hq = (e4 & 31) * 4;
        const float4 w = *(const float4*)(Wa1 + g*128 + hq);
        ushort4 u; u.x = f2b(w.x); u.y = f2b(w.y); u.z = f2b(w.z); u.w = f2b(w.w);
        *(ushort4*)&Wa1s[g*136 + hq] = u;
    }
    // stage Wa0 column block (Wo or Wi) -> LDS bf16 [128][72]
    #pragma unroll
    for (int k = 0; k < 8; ++k) {
        const int e4 = t + k*256;
        const int h = e4 >> 4, dq = (e4 & 15) * 4;
        const float4 w = *(const float4*)(Wa0 + h*192 + 64 + side*64 + dq);
        ushort4 u; u.x = f2b(w.x); u.y = f2b(w.y); u.z = f2b(w.z); u.w = f2b(w.w);
        *(ushort4*)&Wsel[h*72 + dq] = u;
    }
    // stage 16 input rows -> LDS bf16 [16][72]
    {
        const int r = t >> 4, dq = (t & 15) * 4;
        const float* src = side
            ? (ins + b*16384 + (r0 - 256 + r)*64 + dq)
            : (ope + b*16512 + (1 + r0 + r)*64 + dq);
        const float4 w = *(const float4*)src;
        ushort4 u; u.x = f2b(w.x); u.y = f2b(w.y); u.z = f2b(w.z); u.w = f2b(w.w);
        *(ushort4*)&inrows[r*72 + dq] = u;
    }
    __syncthreads();

    const int r = t >> 4;
    const int q = t & 15;

    // P[r][h] = (s2[h] on o-side) + inrow[r] . Wsel[h]
    {
        float acc[8];
        #pragma unroll
        for (int k = 0; k < 8; ++k)
            acc[k] = side ? 0.0f : ws[fb + b*128 + (q + 16*k)];
        #pragma unroll
        for (int d8 = 0; d8 < 64; d8 += 8) {
            float iv[8];
            cvt8(*(const uint4*)&inrows[r*72 + d8], iv);
            #pragma unroll
            for (int k = 0; k < 8; ++k) {
                float wv[8];
                cvt8(*(const uint4*)&Wsel[(q + 16*k)*72 + d8], wv);
                #pragma unroll
                for (int j = 0; j < 8; ++j) acc[k] += wv[j] * iv[j];
            }
        }
        #pragma unroll
        for (int k = 0; k < 8; ++k) P[r*132 + q + 16*k] = acc[k];
    }
    __syncthreads();

    // out[r][g] = P[r] . Wa1[g] (+ ba1 on o-side)
    {
        float acc[8] = {0.f,0.f,0.f,0.f,0.f,0.f,0.f,0.f};
        #pragma unroll
        for (int h8 = 0; h8 < 128; h8 += 8) {
            const float4 p0 = *(const float4*)&P[r*132 + h8];
            const float4 p1 = *(const float4*)&P[r*132 + h8 + 4];
            #pragma unroll
            for (int k = 0; k < 8; ++k) {
                float wv[8];
                cvt8(*(const uint4*)&Wa1s[(q + 16*k)*136 + h8], wv);
                float a = acc[k];
                a += wv[0]*p0.x + wv[1]*p0.y + wv[2]*p0.z + wv[3]*p0.w;
                a += wv[4]*p1.x + wv[5]*p1.y + wv[6]*p1.z + wv[7]*p1.w;
                acc[k] = a;
            }
        }
        if (!side) {
            const int row = b*256 + r0 + r;
            #pragma unroll
            for (int k = 0; k < 8; ++k) {
                const int g = q + 16*k;
                const float v = acc[k] + ba1[g];
                if (MF32) ws[row*128 + g] = v;
                else      ((u16*)ws)[row*128 + g] = f2b(v);
            }
        } else {
            const int row = b*256 + (r0 - 256) + r;
            #pragma unroll
            for (int k = 0; k < 8; ++k) {
                const int g = q + 16*k;
                if (MF32) ws[262144 + row*128 + g] = acc[k];
                else      ((u16*)ws)[262144 + row*128 + g] = f2b(acc[k]);
            }
        }
    }
}

__global__ __launch_bounds__(256) void k2_xy(
    const float* ope, const float* ins, const float* Wa0, const float* Wa1,
    const float* ba1, float* ws, int fb, int mf32)
{
    __shared__ __align__(16) u16 Wa1s[128*136];
    __shared__ __align__(16) u16 Wsel[128*72];
    __shared__ __align__(16) u16 inrows[16*72];
    __shared__ __align__(16) float P[16*132];
    if (mf32) k2_body<true >(ope, ins, Wa0, Wa1, ba1, ws, fb, Wa1s, Wsel, inrows, P);
    else      k2_body<false>(ope, ins, Wa0, Wa1, ba1, ws, fb, Wa1s, Wsel, inrows, P);
}

// ============================================================================
// K3: A[b][o][i] = sum_g lrelu(X2+Y)*w2 + ba2. grid(8*64=512), block(256).
// Output is FP32. Block 0 emits V/hn/cn last.
// ============================================================================
template<bool MF32>
__device__ void k3_body(const float* ws, float* out, int fb)
{
    const int t = threadIdx.x;
    const int b = blockIdx.x >> 6;
    const int o0 = (blockIdx.x & 63) * 4;
    const float* w2  = ws + fb + 1024;
    const float* w2n = ws + fb + 1152;

    float y[128];
    if (MF32) {
        const float* yr = ws + 262144 + (b*256 + t)*128;
        #pragma unroll
        for (int k = 0; k < 32; ++k) *(float4*)&y[k*4] = *(const float4*)(yr + k*4);
    } else {
        const u16* yr = (const u16*)ws + 262144 + (b*256 + t)*128;
        #pragma unroll
        for (int k = 0; k < 16; ++k) cvt8(*(const uint4*)(yr + k*8), &y[k*8]);
    }

    float acc[4] = {0.f, 0.f, 0.f, 0.f};
    #pragma unroll
    for (int gc = 0; gc < 16; ++gc) {
        float wa[8], wb[8];
        { const float4 a0 = *(const float4*)(w2  + gc*8);
          const float4 a1 = *(const float4*)(w2  + gc*8 + 4);
          wa[0]=a0.x; wa[1]=a0.y; wa[2]=a0.z; wa[3]=a0.w;
          wa[4]=a1.x; wa[5]=a1.y; wa[6]=a1.z; wa[7]=a1.w; }
        { const float4 b0 = *(const float4*)(w2n + gc*8);
          const float4 b1 = *(const float4*)(w2n + gc*8 + 4);
          wb[0]=b0.x; wb[1]=b0.y; wb[2]=b0.z; wb[3]=b0.w;
          wb[4]=b1.x; wb[5]=b1.y; wb[6]=b1.z; wb[7]=b1.w; }
        #pragma unroll
        for (int o = 0; o < 4; ++o) {
            float xv[8];
            if (MF32) {
                const float* xr = ws + (b*256 + o0 + o)*128 + gc*8;
                const float4 x0 = *(const float4*)xr;
                const float4 x1 = *(const float4*)(xr + 4);
                xv[0]=x0.x; xv[1]=x0.y; xv[2]=x0.z; xv[3]=x0.w;
                xv[4]=x1.x; xv[5]=x1.y; xv[6]=x1.z; xv[7]=x1.w;
            } else {
                const u16* xr = (const u16*)ws + (b*256 + o0 + o)*128 + gc*8;
                cvt8(*(const uint4*)xr, xv);
            }
            float a = acc[o];
            #pragma unroll
            for (int j = 0; j < 8; ++j) {
                const float v = xv[j] + y[gc*8 + j];
                const float m = fminf(v, 0.f);
                a = fmaf(wa[j], v, fmaf(wb[j], m, a));
            }
            acc[o] = a;
        }
    }
    const float ba2 = ws[fb + 2313];
    #pragma unroll
    for (int o = 0; o < 4; ++o)
        out[8 + b*65536 + (o0 + o)*256 + t] = acc[o] + ba2;

    if (blockIdx.x == 0) {
        if (t < 8) out[t] = ws[fb + 1280 + t];              // V fp32
        #pragma unroll
        for (int j = t; j < 512; j += 256) {
            out[524296 + j] = ws[fb + 1288 + j];            // hn fp32
            out[524808 + j] = ws[fb + 1800 + j];            // cn fp32
        }
    }
}

__global__ __launch_bounds__(256, 2) void k3_adv(const float* ws, float* out,
                                                 int fb, int mf32)
{
    if (mf32) k3_body<true >(ws, out, fb);
    else      k3_body<false>(ws, out, fb);
}

// ============================================================================
extern "C" void kernel_launch(void* const* d_in, const int* in_sizes, int n_in,
                              void* d_out, int out_size, void* d_ws, size_t ws_size,
                              hipStream_t stream) {
    float* ws = (float*)d_ws;
    float* out = (float*)d_out;                 // OUTPUT IS FP32 (round-5 finding)
    const int mf32 = (ws_size >= (size_t)2200000) ? 1 : 0;
    const int fb   = mf32 ? 524288 : 262144;

    const float* ope = (const float*)d_in[0];
    const float* ins = (const float*)d_in[1];

    k1_head<<<dim3(8),   dim3(256), 0, stream>>>(
        ope, (const float*)d_in[2], (const float*)d_in[3],
        (const float*)d_in[4], (const float*)d_in[5],
        (const float*)d_in[6], (const float*)d_in[7],
        (const float*)d_in[8], (const float*)d_in[9],
        (const float*)d_in[10], (const float*)d_in[11],
        (const float*)d_in[12], (const float*)d_in[13],
        (const float*)d_in[14], (const float*)d_in[15],
        (const float*)d_in[18], (const float*)d_in[19], ws, fb);
    k2_xy  <<<dim3(256), dim3(256), 0, stream>>>(
        ope, ins, (const float*)d_in[14], (const float*)d_in[16],
        (const float*)d_in[17], ws, fb, mf32);
    k3_adv <<<dim3(512), dim3(256), 0, stream>>>(ws, out, fb, mf32);
}

// Round 7
// 133.844 us; speedup vs baseline: 1.0224x; 1.0224x over previous
//
#include <hip/hip_runtime.h>
#include <hip/hip_bf16.h>
#include <math.h>

typedef unsigned short u16;

// ---- ws layout (float offsets), fb = staging floats ----
// [0, fb)            : X2 then Y staging (mf32: float; else u16 bf16)
// fb+0    .. +1024   : s2[b][h] (ba0 folded)
// fb+1024 .. +1152   : wa' = 0.505*w2
// fb+1152 .. +1280   : wb' = 0.495*w2
// fb+1280 .. +1288   : V fp32
// fb+1288 .. +1800   : hn fp32
// fb+1800 .. +2312   : cn fp32
// fb+2313            : ba2 fp32
// fb+2320 .. +4368   : C1[b][o] = sum_g wa'*X2 + ba2
// fb+4368 .. +6416   : C2[b][i] = sum_g wa'*Y

__device__ __forceinline__ u16 f2b(float x) { __hip_bfloat16 b = __float2bfloat16(x); return *(u16*)&b; }
__device__ __forceinline__ void cvt8(const uint4 u, float* f) {
    f[0] = __uint_as_float(u.x << 16); f[1] = __uint_as_float(u.x & 0xFFFF0000u);
    f[2] = __uint_as_float(u.y << 16); f[3] = __uint_as_float(u.y & 0xFFFF0000u);
    f[4] = __uint_as_float(u.z << 16); f[5] = __uint_as_float(u.z & 0xFFFF0000u);
    f[6] = __uint_as_float(u.w << 16); f[7] = __uint_as_float(u.w & 0xFFFF0000u);
}

// ============================================================================
// K1: mean -> LSTM -> V head -> s2/w2/ba2 tables. grid(8), block(256). fp32 in.
// ============================================================================
__global__ __launch_bounds__(256) void k1_head(
    const float* __restrict__ ope, const float* __restrict__ hin, const float* __restrict__ cin,
    const float* __restrict__ W_ih, const float* __restrict__ W_hh,
    const float* __restrict__ b_ih, const float* __restrict__ b_hh,
    const float* __restrict__ Wv0, const float* __restrict__ bv0,
    const float* __restrict__ Wv1, const float* __restrict__ bv1,
    const float* __restrict__ Wv2, const float* __restrict__ bv2,
    const float* __restrict__ Wa0, const float* __restrict__ ba0,
    const float* __restrict__ Wa2, const float* __restrict__ ba2,
    float* __restrict__ ws, int fb)
{
    const int b = blockIdx.x, t = threadIdx.x;
    __shared__ float red[256], state[64], hvec[64], gl[256], hn_s[64], t0a[128], t1a[128];

    // state = mean over rows 1..256 of ope_gat[b] (258 rows, slice [1:-1])
    {
        const int d = t & 63, q = t >> 6;
        const float* p = ope + b * 16512 + (1 + q * 64) * 64 + d;
        float s = 0.f;
        #pragma unroll 8
        for (int r = 0; r < 64; ++r) s += p[r * 64];
        red[t] = s;
    }
    __syncthreads();
    if (t < 64)       state[t]   = (red[t] + red[t+64] + red[t+128] + red[t+192]) * (1.f/256.f);
    else if (t < 128) hvec[t-64] = hin[b*64 + (t-64)];
    __syncthreads();

    // gates = state @ W_ih.T + b_ih + h @ W_hh.T + b_hh
    {
        float g = b_ih[t] + b_hh[t];
        #pragma unroll 8
        for (int d = 0; d < 64; ++d)
            g += state[d] * W_ih[t*64 + d] + hvec[d] * W_hh[t*64 + d];
        gl[t] = g;
    }
    __syncthreads();

    // LSTM cell, split order i,f,g,o
    if (t < 64) {
        const float ig = gl[t], fg = gl[64+t], gg = gl[128+t], og = gl[192+t];
        const float c  = cin[b*64 + t];
        const float si = 1.f/(1.f + expf(-ig));
        const float sf = 1.f/(1.f + expf(-fg));
        const float so = 1.f/(1.f + expf(-og));
        const float cn = sf*c + si*tanhf(gg);
        const float hn = so*tanhf(cn);
        ws[fb + 1288 + b*64 + t] = hn;
        ws[fb + 1800 + b*64 + t] = cn;
        hn_s[t] = hn;
    }
    __syncthreads();

    // V layer 0 (no activation per reference): t0a = hn @ Wv0.T + bv0
    if (t < 128) {
        float a = bv0[t];
        #pragma unroll 8
        for (int d = 0; d < 64; ++d) a += hn_s[d] * Wv0[t*64 + d];
        t0a[t] = a;
    }
    __syncthreads();
    if (t < 128) {
        float a = bv1[t];
        #pragma unroll 8
        for (int d = 0; d < 128; ++d) a += t0a[d] * Wv1[t*128 + d];
        a = (a >= 0.f) ? a : 0.01f*a;
        t1a[t] = a * Wv2[t];
        float s2 = ba0[t];
        #pragma unroll 8
        for (int d = 0; d < 64; ++d) s2 += hn_s[d] * Wa0[t*192 + d];
        ws[fb + b*128 + t] = s2;
        const float w2v = Wa2[t];
        ws[fb + 1024 + t] = 0.505f * w2v;   // wa'
        ws[fb + 1152 + t] = 0.495f * w2v;   // wb'
    }
    __syncthreads();
    if (t == 0) {
        float v = bv2[0];
        for (int g = 0; g < 128; ++g) v += t1a[g];
        ws[fb + 1280 + b] = v;
        ws[fb + 2313]    = ba2[0];
    }
}

// ============================================================================
// K2: X2[b][o][g], Y[b][i][g] + rank-1 reductions C1[b][o], C2[b][i].
// grid(8*32=256), block(256). rows 0..255 o-side, 256..511 i-side.
// ============================================================================
template<bool MF32>
__device__ void k2_body(const float* ope, const float* ins, const float* Wa0,
    const float* Wa1, const float* ba1, float* ws, int fb,
    u16* Wa1s, u16* Wsel, u16* inrows, float* P)
{
    const int t = threadIdx.x;
    const int b = blockIdx.x >> 5;
    const int r0 = (blockIdx.x & 31) * 16;
    const int side = (r0 >= 256) ? 1 : 0;

    // stage Wa1 -> LDS bf16 [128][136]
    #pragma unroll
    for (int k = 0; k < 16; ++k) {
        const int e4 = t + k*256;
        const int g = e4 >> 5, hq = (e4 & 31) * 4;
        const float4 w = *(const float4*)(Wa1 + g*128 + hq);
        ushort4 u; u.x = f2b(w.x); u.y = f2b(w.y); u.z = f2b(w.z); u.w = f2b(w.w);
        *(ushort4*)&Wa1s[g*136 + hq] = u;
    }
    // stage Wa0 column block (Wo or Wi) -> LDS bf16 [128][72]
    #pragma unroll
    for (int k = 0; k < 8; ++k) {
        const int e4 = t + k*256;
        const int h = e4 >> 4, dq = (e4 & 15) * 4;
        const float4 w = *(const float4*)(Wa0 + h*192 + 64 + side*64 + dq);
        ushort4 u; u.x = f2b(w.x); u.y = f2b(w.y); u.z = f2b(w.z); u.w = f2b(w.w);
        *(ushort4*)&Wsel[h*72 + dq] = u;
    }
    // stage 16 input rows -> LDS bf16 [16][72]
    {
        const int r = t >> 4, dq = (t & 15) * 4;
        const float* src = side
            ? (ins + b*16384 + (r0 - 256 + r)*64 + dq)
            : (ope + b*16512 + (1 + r0 + r)*64 + dq);
        const float4 w = *(const float4*)src;
        ushort4 u; u.x = f2b(w.x); u.y = f2b(w.y); u.z = f2b(w.z); u.w = f2b(w.w);
        *(ushort4*)&inrows[r*72 + dq] = u;
    }
    __syncthreads();

    const int r = t >> 4;
    const int q = t & 15;

    // P[r][h] = (s2[h] on o-side) + inrow[r] . Wsel[h]
    {
        float acc[8];
        #pragma unroll
        for (int k = 0; k < 8; ++k)
            acc[k] = side ? 0.0f : ws[fb + b*128 + (q + 16*k)];
        #pragma unroll
        for (int d8 = 0; d8 < 64; d8 += 8) {
            float iv[8];
            cvt8(*(const uint4*)&inrows[r*72 + d8], iv);
            #pragma unroll
            for (int k = 0; k < 8; ++k) {
                float wv[8];
                cvt8(*(const uint4*)&Wsel[(q + 16*k)*72 + d8], wv);
                #pragma unroll
                for (int j = 0; j < 8; ++j) acc[k] += wv[j] * iv[j];
            }
        }
        #pragma unroll
        for (int k = 0; k < 8; ++k) P[r*132 + q + 16*k] = acc[k];
    }
    __syncthreads();

    // out[r][g] = P[r] . Wa1[g] (+ ba1 on o-side); then C-reduce over g
    {
        float acc[8] = {0.f,0.f,0.f,0.f,0.f,0.f,0.f,0.f};
        #pragma unroll
        for (int h8 = 0; h8 < 128; h8 += 8) {
            const float4 p0 = *(const float4*)&P[r*132 + h8];
            const float4 p1 = *(const float4*)&P[r*132 + h8 + 4];
            #pragma unroll
            for (int k = 0; k < 8; ++k) {
                float wv[8];
                cvt8(*(const uint4*)&Wa1s[(q + 16*k)*136 + h8], wv);
                float a = acc[k];
                a += wv[0]*p0.x + wv[1]*p0.y + wv[2]*p0.z + wv[3]*p0.w;
                a += wv[4]*p1.x + wv[5]*p1.y + wv[6]*p1.z + wv[7]*p1.w;
                acc[k] = a;
            }
        }
        float part = 0.f;
        if (!side) {
            const int row = b*256 + r0 + r;
            #pragma unroll
            for (int k = 0; k < 8; ++k) {
                const int g = q + 16*k;
                const float v = acc[k] + ba1[g];
                part = fmaf(ws[fb + 1024 + g], v, part);    // wa' * X2
                if (MF32) ws[row*128 + g] = v;
                else      ((u16*)ws)[row*128 + g] = f2b(v);
            }
        } else {
            const int row = b*256 + (r0 - 256) + r;
            #pragma unroll
            for (int k = 0; k < 8; ++k) {
                const int g = q + 16*k;
                part = fmaf(ws[fb + 1024 + g], acc[k], part); // wa' * Y
                if (MF32) ws[262144 + row*128 + g] = acc[k];
                else      ((u16*)ws)[262144 + row*128 + g] = f2b(acc[k]);
            }
        }
        // 16-lane shuffle reduce (row lanes are 16-aligned within the wave)
        part += __shfl_xor(part, 1);
        part += __shfl_xor(part, 2);
        part += __shfl_xor(part, 4);
        part += __shfl_xor(part, 8);
        if (q == 0) {
            if (!side) ws[fb + 2320 + b*256 + r0 + r] = part + ws[fb + 2313]; // +ba2
            else       ws[fb + 4368 + b*256 + (r0 - 256) + r] = part;
        }
    }
}

__global__ __launch_bounds__(256) void k2_xy(
    const float* ope, const float* ins, const float* Wa0, const float* Wa1,
    const float* ba1, float* ws, int fb, int mf32)
{
    __shared__ __align__(16) u16 Wa1s[128*136];
    __shared__ __align__(16) u16 Wsel[128*72];
    __shared__ __align__(16) u16 inrows[16*72];
    __shared__ __align__(16) float P[16*132];
    if (mf32) k2_body<true >(ope, ins, Wa0, Wa1, ba1, ws, fb, Wa1s, Wsel, inrows, P);
    else      k2_body<false>(ope, ins, Wa0, Wa1, ba1, ws, fb, Wa1s, Wsel, inrows, P);
}

// ============================================================================
// K3: A[b][o][i] = C1[b,o] + C2[b,i] + sum_g wb'[g]*|X2+Y|.
// grid(8*64=512), block(256). 2 VALU/element (add + fma-with-abs).
// ============================================================================
template<bool MF32>
__device__ void k3_body(const float* ws, float* out, int fb)
{
    const int t = threadIdx.x;
    const int b = blockIdx.x >> 6;
    const int o0 = (blockIdx.x & 63) * 4;
    const float* wb = ws + fb + 1152;

    float acc[4] = {0.f, 0.f, 0.f, 0.f};
    #pragma unroll
    for (int gc = 0; gc < 8; ++gc) {              // 16 g per chunk
        float yv[16], wv[16];
        if (MF32) {
            const float* yr = ws + 262144 + (b*256 + t)*128 + gc*16;
            #pragma unroll
            for (int k = 0; k < 4; ++k) *(float4*)&yv[k*4] = *(const float4*)(yr + k*4);
        } else {
            const u16* yr = (const u16*)ws + 262144 + (b*256 + t)*128 + gc*16;
            cvt8(*(const uint4*)yr, yv);
            cvt8(*(const uint4*)(yr + 8), yv + 8);
        }
        #pragma unroll
        for (int k = 0; k < 4; ++k) *(float4*)&wv[k*4] = *(const float4*)(wb + gc*16 + k*4);
        #pragma unroll
        for (int o = 0; o < 4; ++o) {
            float xv[16];
            if (MF32) {
                const float* xr = ws + (b*256 + o0 + o)*128 + gc*16;   // uniform
                #pragma unroll
                for (int k = 0; k < 4; ++k) *(float4*)&xv[k*4] = *(const float4*)(xr + k*4);
            } else {
                const u16* xr = (const u16*)ws + (b*256 + o0 + o)*128 + gc*16;
                cvt8(*(const uint4*)xr, xv);
                cvt8(*(const uint4*)(xr + 8), xv + 8);
            }
            float a = acc[o];
            #pragma unroll
            for (int j = 0; j < 16; ++j)
                a = fmaf(wv[j], fabsf(xv[j] + yv[j]), a);
            acc[o] = a;
        }
    }
    const float c2 = ws[fb + 4368 + b*256 + t];
    #pragma unroll
    for (int o = 0; o < 4; ++o)
        out[8 + b*65536 + (o0 + o)*256 + t] = ws[fb + 2320 + b*256 + o0 + o] + c2 + acc[o];

    if (blockIdx.x == 0) {
        if (t < 8) out[t] = ws[fb + 1280 + t];              // V fp32
        #pragma unroll
        for (int j = t; j < 512; j += 256) {
            out[524296 + j] = ws[fb + 1288 + j];            // hn fp32
            out[524808 + j] = ws[fb + 1800 + j];            // cn fp32
        }
    }
}

__global__ __launch_bounds__(256) void k3_adv(const float* ws, float* out,
                                              int fb, int mf32)
{
    if (mf32) k3_body<true >(ws, out, fb);
    else      k3_body<false>(ws, out, fb);
}

// ============================================================================
extern "C" void kernel_launch(void* const* d_in, const int* in_sizes, int n_in,
                              void* d_out, int out_size, void* d_ws, size_t ws_size,
                              hipStream_t stream) {
    float* ws = (float*)d_ws;
    float* out = (float*)d_out;                 // output is fp32
    const int mf32 = (ws_size >= (size_t)2200000) ? 1 : 0;
    const int fb   = mf32 ? 524288 : 262144;

    const float* ope = (const float*)d_in[0];
    const float* ins = (const float*)d_in[1];

    k1_head<<<dim3(8),   dim3(256), 0, stream>>>(
        ope, (const float*)d_in[2], (const float*)d_in[3],
        (const float*)d_in[4], (const float*)d_in[5],
        (const float*)d_in[6], (const float*)d_in[7],
        (const float*)d_in[8], (const float*)d_in[9],
        (const float*)d_in[10], (const float*)d_in[11],
        (const float*)d_in[12], (const float*)d_in[13],
        (const float*)d_in[14], (const float*)d_in[15],
        (const float*)d_in[18], (const float*)d_in[19], ws, fb);
    k2_xy  <<<dim3(256), dim3(256), 0, stream>>>(
        ope, ins, (const float*)d_in[14], (const float*)d_in[16],
        (const float*)d_in[17], ws, fb, mf32);
    k3_adv <<<dim3(512), dim3(256), 0, stream>>>(ws, out, fb, mf32);
}

// Round 8
// 132.251 us; speedup vs baseline: 1.0347x; 1.0120x over previous
//
#include <hip/hip_runtime.h>
#include <hip/hip_bf16.h>
#include <math.h>

typedef unsigned short u16;

// ---- ws layout (float offsets), fb = staging floats ----
// [0, fb)            : X2 then Y staging (mf32: float; else u16 bf16)
// fb+0    .. +1024   : s2[b][h] (ba0 folded)
// fb+1024 .. +1152   : wa' = 0.505*w2
// fb+1152 .. +1280   : wb' = 0.495*w2
// fb+1280 .. +1288   : V fp32
// fb+1288 .. +1800   : hn fp32
// fb+1800 .. +2312   : cn fp32
// fb+2313            : ba2 fp32
// fb+2320 .. +4368   : C1[b][o] = sum_g wa'*X2 + ba2
// fb+4368 .. +6416   : C2[b][i] = sum_g wa'*Y
// fb+6416 .. +10512  : mean partials [8 b][8 slice][64 d]
// fb+10512.. +18704  : Wa1 bf16 (16384 u16, dense [128 g][128 h])
// fb+18704.. +22800  : Wo  bf16 (8192 u16, dense [128 h][64 d])
// fb+22800.. +26896  : Wi  bf16 (8192 u16, dense [128 h][64 d])
#define PART  6416
#define WA1B  10512
#define WOB   18704
#define WIB   22800

__device__ __forceinline__ u16 f2b(float x) { __hip_bfloat16 b = __float2bfloat16(x); return *(u16*)&b; }
__device__ __forceinline__ void cvt8(const uint4 u, float* f) {
    f[0] = __uint_as_float(u.x << 16); f[1] = __uint_as_float(u.x & 0xFFFF0000u);
    f[2] = __uint_as_float(u.y << 16); f[3] = __uint_as_float(u.y & 0xFFFF0000u);
    f[4] = __uint_as_float(u.z << 16); f[5] = __uint_as_float(u.z & 0xFFFF0000u);
    f[6] = __uint_as_float(u.w << 16); f[7] = __uint_as_float(u.w & 0xFFFF0000u);
}
__device__ __forceinline__ float dot4(const float4 a, const float4 b) {
    return a.x*b.x + a.y*b.y + a.z*b.z + a.w*b.w;
}

// ============================================================================
// K0: (blocks 0..63) mean partials over ope rows; (blocks 64..79) fp32->bf16
// weight conversion of Wa1 / Wo / Wi into ws. grid(80), block(256).
// ============================================================================
__global__ __launch_bounds__(256) void k0_pre(
    const float* __restrict__ ope, const float* __restrict__ Wa0,
    const float* __restrict__ Wa1, float* __restrict__ ws, int fb)
{
    const int t = threadIdx.x;
    if (blockIdx.x < 64) {
        const int b = blockIdx.x >> 3, s = blockIdx.x & 7;
        const int d = t & 63, rg = t >> 6;
        __shared__ float red[256];
        const float* p = ope + b*16512 + (1 + s*32 + rg*8)*64 + d;
        float acc = 0.f;
        #pragma unroll
        for (int rr = 0; rr < 8; ++rr) acc += p[rr*64];
        red[t] = acc;
        __syncthreads();
        if (t < 64)
            ws[fb + PART + (b*8 + s)*64 + t] = red[t] + red[t+64] + red[t+128] + red[t+192];
    } else {
        // 16 blocks x 256 thr x 8 elems = 32768 conversions
        const int e0 = ((blockIdx.x - 64)*256 + t) * 8;
        const float* src;
        u16* dst;
        if (e0 < 16384)      { src = Wa1 + e0;                                      dst = (u16*)(ws + fb + WA1B) + e0; }
        else if (e0 < 24576) { const int i = e0 - 16384; src = Wa0 + (i>>6)*192 + 64  + (i&63); dst = (u16*)(ws + fb + WOB) + i; }
        else                 { const int i = e0 - 24576; src = Wa0 + (i>>6)*192 + 128 + (i&63); dst = (u16*)(ws + fb + WIB) + i; }
        const float4 a = *(const float4*)src;
        const float4 c = *(const float4*)(src + 4);
        ushort4 u0; u0.x = f2b(a.x); u0.y = f2b(a.y); u0.z = f2b(a.z); u0.w = f2b(a.w);
        ushort4 u1; u1.x = f2b(c.x); u1.y = f2b(c.y); u1.z = f2b(c.z); u1.w = f2b(c.w);
        *(ushort4*)dst = u0;
        *(ushort4*)(dst + 4) = u1;
    }
}

// ============================================================================
// K1: LSTM -> V head -> s2/w2/ba2 tables. grid(8), block(256). Mean from
// k0 partials; float4 weight-row loads; wave-reduce for V.
// ============================================================================
__global__ __launch_bounds__(256) void k1_head(
    const float* __restrict__ hin, const float* __restrict__ cin,
    const float* __restrict__ W_ih, const float* __restrict__ W_hh,
    const float* __restrict__ b_ih, const float* __restrict__ b_hh,
    const float* __restrict__ Wv0, const float* __restrict__ bv0,
    const float* __restrict__ Wv1, const float* __restrict__ bv1,
    const float* __restrict__ Wv2, const float* __restrict__ bv2,
    const float* __restrict__ Wa0, const float* __restrict__ ba0,
    const float* __restrict__ Wa2, const float* __restrict__ ba2,
    float* __restrict__ ws, int fb)
{
    const int b = blockIdx.x, t = threadIdx.x;
    __shared__ __align__(16) float state[64], hvec[64], gl[256], hn_s[64], t0a[128], t1a[128];

    if (t < 64) {
        float s = 0.f;
        #pragma unroll
        for (int s8 = 0; s8 < 8; ++s8) s += ws[fb + PART + (b*8 + s8)*64 + t];
        state[t] = s * (1.f/256.f);
    } else if (t < 128) hvec[t-64] = hin[b*64 + (t-64)];
    __syncthreads();

    // gates = state @ W_ih.T + b_ih + h @ W_hh.T + b_hh   (float4 rows)
    {
        float g = b_ih[t] + b_hh[t];
        const float4* wi = (const float4*)(W_ih + t*64);
        const float4* wh = (const float4*)(W_hh + t*64);
        #pragma unroll
        for (int k = 0; k < 16; ++k)
            g += dot4(wi[k], *(const float4*)&state[k*4])
               + dot4(wh[k], *(const float4*)&hvec[k*4]);
        gl[t] = g;
    }
    __syncthreads();

    // LSTM cell, split order i,f,g,o
    if (t < 64) {
        const float ig = gl[t], fg = gl[64+t], gg = gl[128+t], og = gl[192+t];
        const float c  = cin[b*64 + t];
        const float si = 1.f/(1.f + expf(-ig));
        const float sf = 1.f/(1.f + expf(-fg));
        const float so = 1.f/(1.f + expf(-og));
        const float cn = sf*c + si*tanhf(gg);
        const float hn = so*tanhf(cn);
        ws[fb + 1288 + b*64 + t] = hn;
        ws[fb + 1800 + b*64 + t] = cn;
        hn_s[t] = hn;
    }
    __syncthreads();

    // V layer 0 (no activation per reference)
    if (t < 128) {
        float a = bv0[t];
        const float4* w = (const float4*)(Wv0 + t*64);
        #pragma unroll
        for (int k = 0; k < 16; ++k) a += dot4(w[k], *(const float4*)&hn_s[k*4]);
        t0a[t] = a;
    }
    __syncthreads();
    if (t < 128) {
        float a = bv1[t];
        const float4* w = (const float4*)(Wv1 + t*128);
        #pragma unroll
        for (int k = 0; k < 32; ++k) a += dot4(w[k], *(const float4*)&t0a[k*4]);
        a = (a >= 0.f) ? a : 0.01f*a;
        t1a[t] = a * Wv2[t];
        float s2 = ba0[t];
        const float4* w0 = (const float4*)(Wa0 + t*192);
        #pragma unroll
        for (int k = 0; k < 16; ++k) s2 += dot4(w0[k], *(const float4*)&hn_s[k*4]);
        ws[fb + b*128 + t] = s2;
        const float w2v = Wa2[t];
        ws[fb + 1024 + t] = 0.505f * w2v;   // wa'
        ws[fb + 1152 + t] = 0.495f * w2v;   // wb'
    }
    __syncthreads();
    if (t < 64) {                            // wave 0 shuffle-reduce for V
        float v = t1a[t] + t1a[t + 64];
        v += __shfl_xor(v, 32); v += __shfl_xor(v, 16); v += __shfl_xor(v, 8);
        v += __shfl_xor(v, 4);  v += __shfl_xor(v, 2);  v += __shfl_xor(v, 1);
        if (t == 0) {
            ws[fb + 1280 + b] = v + bv2[0];
            ws[fb + 2313]    = ba2[0];
        }
    }
}

// ============================================================================
// K2: X2[b][o][g], Y[b][i][g] + rank-1 reductions C1, C2. grid(256), block(256).
// Weights staged from k0's bf16 copies (pure uint4 moves).
// ============================================================================
template<bool MF32>
__device__ void k2_body(const float* ope, const float* ins, const float* ba1,
    float* ws, int fb, u16* Wa1s, u16* Wsel, u16* inrows, float* P)
{
    const int t = threadIdx.x;
    const int b = blockIdx.x >> 5;
    const int r0 = (blockIdx.x & 31) * 16;
    const int side = (r0 >= 256) ? 1 : 0;

    // stage Wa1 bf16 [128][136] from precomputed
    {
        const u16* wa1b = (const u16*)(ws + fb + WA1B);
        #pragma unroll
        for (int k = 0; k < 8; ++k) {
            const int e4 = t + k*256;
            const int g = e4 >> 4, hq = (e4 & 15) * 8;
            *(uint4*)&Wa1s[g*136 + hq] = *(const uint4*)(wa1b + g*128 + hq);
        }
    }
    // stage Wo/Wi bf16 [128][72] from precomputed
    {
        const u16* wsb = (const u16*)(ws + fb + (side ? WIB : WOB));
        #pragma unroll
        for (int k = 0; k < 4; ++k) {
            const int e4 = t + k*256;
            const int h = e4 >> 3, dq = (e4 & 7) * 8;
            *(uint4*)&Wsel[h*72 + dq] = *(const uint4*)(wsb + h*64 + dq);
        }
    }
    // stage 16 input rows -> LDS bf16 [16][72]
    {
        const int r = t >> 4, dq = (t & 15) * 4;
        const float* src = side
            ? (ins + b*16384 + (r0 - 256 + r)*64 + dq)
            : (ope + b*16512 + (1 + r0 + r)*64 + dq);
        const float4 w = *(const float4*)src;
        ushort4 u; u.x = f2b(w.x); u.y = f2b(w.y); u.z = f2b(w.z); u.w = f2b(w.w);
        *(ushort4*)&inrows[r*72 + dq] = u;
    }
    __syncthreads();

    const int r = t >> 4;
    const int q = t & 15;

    // P[r][h] = (s2[h] on o-side) + inrow[r] . Wsel[h]
    {
        float acc[8];
        #pragma unroll
        for (int k = 0; k < 8; ++k)
            acc[k] = side ? 0.0f : ws[fb + b*128 + (q + 16*k)];
        #pragma unroll
        for (int d8 = 0; d8 < 64; d8 += 8) {
            float iv[8];
            cvt8(*(const uint4*)&inrows[r*72 + d8], iv);
            #pragma unroll
            for (int k = 0; k < 8; ++k) {
                float wv[8];
                cvt8(*(const uint4*)&Wsel[(q + 16*k)*72 + d8], wv);
                #pragma unroll
                for (int j = 0; j < 8; ++j) acc[k] += wv[j] * iv[j];
            }
        }
        #pragma unroll
        for (int k = 0; k < 8; ++k) P[r*132 + q + 16*k] = acc[k];
    }
    __syncthreads();

    // out[r][g] = P[r] . Wa1[g] (+ ba1 on o-side); then C-reduce over g
    {
        float acc[8] = {0.f,0.f,0.f,0.f,0.f,0.f,0.f,0.f};
        #pragma unroll
        for (int h8 = 0; h8 < 128; h8 += 8) {
            const float4 p0 = *(const float4*)&P[r*132 + h8];
            const float4 p1 = *(const float4*)&P[r*132 + h8 + 4];
            #pragma unroll
            for (int k = 0; k < 8; ++k) {
                float wv[8];
                cvt8(*(const uint4*)&Wa1s[(q + 16*k)*136 + h8], wv);
                float a = acc[k];
                a += wv[0]*p0.x + wv[1]*p0.y + wv[2]*p0.z + wv[3]*p0.w;
                a += wv[4]*p1.x + wv[5]*p1.y + wv[6]*p1.z + wv[7]*p1.w;
                acc[k] = a;
            }
        }
        float part = 0.f;
        if (!side) {
            const int row = b*256 + r0 + r;
            #pragma unroll
            for (int k = 0; k < 8; ++k) {
                const int g = q + 16*k;
                const float v = acc[k] + ba1[g];
                part = fmaf(ws[fb + 1024 + g], v, part);      // wa' * X2
                if (MF32) ws[row*128 + g] = v;
                else      ((u16*)ws)[row*128 + g] = f2b(v);
            }
        } else {
            const int row = b*256 + (r0 - 256) + r;
            #pragma unroll
            for (int k = 0; k < 8; ++k) {
                const int g = q + 16*k;
                part = fmaf(ws[fb + 1024 + g], acc[k], part); // wa' * Y
                if (MF32) ws[262144 + row*128 + g] = acc[k];
                else      ((u16*)ws)[262144 + row*128 + g] = f2b(acc[k]);
            }
        }
        part += __shfl_xor(part, 1);
        part += __shfl_xor(part, 2);
        part += __shfl_xor(part, 4);
        part += __shfl_xor(part, 8);
        if (q == 0) {
            if (!side) ws[fb + 2320 + b*256 + r0 + r] = part + ws[fb + 2313]; // +ba2
            else       ws[fb + 4368 + b*256 + (r0 - 256) + r] = part;
        }
    }
}

__global__ __launch_bounds__(256) void k2_xy(
    const float* ope, const float* ins, const float* ba1,
    float* ws, int fb, int mf32)
{
    __shared__ __align__(16) u16 Wa1s[128*136];
    __shared__ __align__(16) u16 Wsel[128*72];
    __shared__ __align__(16) u16 inrows[16*72];
    __shared__ __align__(16) float P[16*132];
    if (mf32) k2_body<true >(ope, ins, ba1, ws, fb, Wa1s, Wsel, inrows, P);
    else      k2_body<false>(ope, ins, ba1, ws, fb, Wa1s, Wsel, inrows, P);
}

// ============================================================================
// K3: A[b][o][i] = C1[b,o] + C2[b,i] + sum_g wb'[g]*|X2+Y|. grid(512), block(256).
// ============================================================================
template<bool MF32>
__device__ void k3_body(const float* ws, float* out, int fb)
{
    const int t = threadIdx.x;
    const int b = blockIdx.x >> 6;
    const int o0 = (blockIdx.x & 63) * 4;
    const float* wb = ws + fb + 1152;

    float acc[4] = {0.f, 0.f, 0.f, 0.f};
    #pragma unroll
    for (int gc = 0; gc < 8; ++gc) {              // 16 g per chunk
        float yv[16], wv[16];
        if (MF32) {
            const float* yr = ws + 262144 + (b*256 + t)*128 + gc*16;
            #pragma unroll
            for (int k = 0; k < 4; ++k) *(float4*)&yv[k*4] = *(const float4*)(yr + k*4);
        } else {
            const u16* yr = (const u16*)ws + 262144 + (b*256 + t)*128 + gc*16;
            cvt8(*(const uint4*)yr, yv);
            cvt8(*(const uint4*)(yr + 8), yv + 8);
        }
        #pragma unroll
        for (int k = 0; k < 4; ++k) *(float4*)&wv[k*4] = *(const float4*)(wb + gc*16 + k*4);
        #pragma unroll
        for (int o = 0; o < 4; ++o) {
            float xv[16];
            if (MF32) {
                const float* xr = ws + (b*256 + o0 + o)*128 + gc*16;   // uniform
                #pragma unroll
                for (int k = 0; k < 4; ++k) *(float4*)&xv[k*4] = *(const float4*)(xr + k*4);
            } else {
                const u16* xr = (const u16*)ws + (b*256 + o0 + o)*128 + gc*16;
                cvt8(*(const uint4*)xr, xv);
                cvt8(*(const uint4*)(xr + 8), xv + 8);
            }
            float a = acc[o];
            #pragma unroll
            for (int j = 0; j < 16; ++j)
                a = fmaf(wv[j], fabsf(xv[j] + yv[j]), a);
            acc[o] = a;
        }
    }
    const float c2 = ws[fb + 4368 + b*256 + t];
    #pragma unroll
    for (int o = 0; o < 4; ++o)
        out[8 + b*65536 + (o0 + o)*256 + t] = ws[fb + 2320 + b*256 + o0 + o] + c2 + acc[o];

    if (blockIdx.x == 0) {
        if (t < 8) out[t] = ws[fb + 1280 + t];              // V fp32
        #pragma unroll
        for (int j = t; j < 512; j += 256) {
            out[524296 + j] = ws[fb + 1288 + j];            // hn fp32
            out[524808 + j] = ws[fb + 1800 + j];            // cn fp32
        }
    }
}

__global__ __launch_bounds__(256) void k3_adv(const float* ws, float* out,
                                              int fb, int mf32)
{
    if (mf32) k3_body<true >(ws, out, fb);
    else      k3_body<false>(ws, out, fb);
}

// ============================================================================
extern "C" void kernel_launch(void* const* d_in, const int* in_sizes, int n_in,
                              void* d_out, int out_size, void* d_ws, size_t ws_size,
                              hipStream_t stream) {
    float* ws = (float*)d_ws;
    float* out = (float*)d_out;                 // output is fp32
    const int mf32 = (ws_size >= (size_t)2400000) ? 1 : 0;
    const int fb   = mf32 ? 524288 : 262144;

    const float* ope = (const float*)d_in[0];
    const float* ins = (const float*)d_in[1];

    k0_pre <<<dim3(80),  dim3(256), 0, stream>>>(
        ope, (const float*)d_in[14], (const float*)d_in[16], ws, fb);
    k1_head<<<dim3(8),   dim3(256), 0, stream>>>(
        (const float*)d_in[2], (const float*)d_in[3],
        (const float*)d_in[4], (const float*)d_in[5],
        (const float*)d_in[6], (const float*)d_in[7],
        (const float*)d_in[8], (const float*)d_in[9],
        (const float*)d_in[10], (const float*)d_in[11],
        (const float*)d_in[12], (const float*)d_in[13],
        (const float*)d_in[14], (const float*)d_in[15],
        (const float*)d_in[18], (const float*)d_in[19], ws, fb);
    k2_xy  <<<dim3(256), dim3(256), 0, stream>>>(
        ope, ins, (const float*)d_in[17], ws, fb, mf32);
    k3_adv <<<dim3(512), dim3(256), 0, stream>>>(ws, out, fb, mf32);
}

// Round 9
// 123.209 us; speedup vs baseline: 1.1107x; 1.0734x over previous
//
#include <hip/hip_runtime.h>
#include <hip/hip_bf16.h>
#include <math.h>

typedef unsigned short u16;

// ---- ws layout (float offsets), fb = 524288 (fp32 staging; ws is 256 MiB) ----
// [0, 262144)        : PO[b][o][g] fp32
// [262144, 524288)   : Y[b][i][g] fp32
// fb+1024 .. +1152   : wa' = 0.505*w2          (k0)
// fb+1152 .. +1280   : wb' = 0.495*w2          (k0)
// fb+1280 .. +1288   : V fp32                  (k12)
// fb+1288 .. +1800   : hn fp32                 (k12)
// fb+1800 .. +2312   : cn fp32                 (k12)
// fb+2313            : ba2 fp32                (k0)
// fb+2320 .. +4368   : C1PO[b][o] = sum_g wa'*PO        (k12)
// fb+4368 .. +6416   : C2[b][i]   = sum_g wa'*Y         (k12)
// fb+6416 .. +10512  : mean partials [8 b][8 slice][64 d] (k0)
// fb+10512.. +18704  : Wa1 bf16 (16384 u16)             (k0)
// fb+18704.. +22800  : Wo  bf16 (8192 u16)              (k0)
// fb+22800.. +26896  : Wi  bf16 (8192 u16)              (k0)
// fb+26896.. +27920  : S[b][g] = s2.Wa1 + ba1           (k12)
// fb+27920.. +27928  : C1S[b] = sum_g wa'*S + ba2       (k12)
#define FB    524288
#define PART  6416
#define WA1B  10512
#define WOB   18704
#define WIB   22800
#define SOFF  26896
#define C1S   27920

__device__ __forceinline__ u16 f2b(float x) { __hip_bfloat16 b = __float2bfloat16(x); return *(u16*)&b; }
__device__ __forceinline__ void cvt8(const uint4 u, float* f) {
    f[0] = __uint_as_float(u.x << 16); f[1] = __uint_as_float(u.x & 0xFFFF0000u);
    f[2] = __uint_as_float(u.y << 16); f[3] = __uint_as_float(u.y & 0xFFFF0000u);
    f[4] = __uint_as_float(u.z << 16); f[5] = __uint_as_float(u.z & 0xFFFF0000u);
    f[6] = __uint_as_float(u.w << 16); f[7] = __uint_as_float(u.w & 0xFFFF0000u);
}
__device__ __forceinline__ float dot4(const float4 a, const float4 b) {
    return a.x*b.x + a.y*b.y + a.z*b.z + a.w*b.w;
}

// ============================================================================
// K0: blocks 0..63 mean partials; 64..79 weight fp32->bf16; 80 w2/ba2 tables.
// grid(81), block(256). Depends only on inputs.
// ============================================================================
__global__ __launch_bounds__(256) void k0_pre(
    const float* __restrict__ ope, const float* __restrict__ Wa0,
    const float* __restrict__ Wa1, const float* __restrict__ Wa2,
    const float* __restrict__ ba2, float* __restrict__ ws)
{
    const int t = threadIdx.x;
    if (blockIdx.x < 64) {
        const int b = blockIdx.x >> 3, s = blockIdx.x & 7;
        const int d = t & 63, rg = t >> 6;
        __shared__ float red[256];
        const float* p = ope + b*16512 + (1 + s*32 + rg*8)*64 + d;
        float acc = 0.f;
        #pragma unroll
        for (int rr = 0; rr < 8; ++rr) acc += p[rr*64];
        red[t] = acc;
        __syncthreads();
        if (t < 64)
            ws[FB + PART + (b*8 + s)*64 + t] = red[t] + red[t+64] + red[t+128] + red[t+192];
    } else if (blockIdx.x < 80) {
        const int e0 = ((blockIdx.x - 64)*256 + t) * 8;
        const float* src;
        u16* dst;
        if (e0 < 16384)      { src = Wa1 + e0;                                              dst = (u16*)(ws + FB + WA1B) + e0; }
        else if (e0 < 24576) { const int i = e0 - 16384; src = Wa0 + (i>>6)*192 + 64  + (i&63); dst = (u16*)(ws + FB + WOB) + i; }
        else                 { const int i = e0 - 24576; src = Wa0 + (i>>6)*192 + 128 + (i&63); dst = (u16*)(ws + FB + WIB) + i; }
        const float4 a = *(const float4*)src;
        const float4 c = *(const float4*)(src + 4);
        ushort4 u0; u0.x = f2b(a.x); u0.y = f2b(a.y); u0.z = f2b(a.z); u0.w = f2b(a.w);
        ushort4 u1; u1.x = f2b(c.x); u1.y = f2b(c.y); u1.z = f2b(c.z); u1.w = f2b(c.w);
        *(ushort4*)dst = u0;
        *(ushort4*)(dst + 4) = u1;
    } else {
        if (t < 128) {
            const float w2v = Wa2[t];
            ws[FB + 1024 + t] = 0.505f * w2v;
            ws[FB + 1152 + t] = 0.495f * w2v;
        }
        if (t == 128) ws[FB + 2313] = ba2[0];
    }
}

// ============================================================================
// K12: blocks 0..255 = PO/Y tiles (+C1PO/C2 reduces); blocks 256..263 = LSTM,
// V head, S[b][g], C1S[b]. grid(264), block(256). Depends only on k0.
// ============================================================================
__global__ __launch_bounds__(256) void k12_main(
    const float* __restrict__ ope, const float* __restrict__ ins,
    const float* __restrict__ hin, const float* __restrict__ cin,
    const float* __restrict__ W_ih, const float* __restrict__ W_hh,
    const float* __restrict__ b_ih, const float* __restrict__ b_hh,
    const float* __restrict__ Wv0, const float* __restrict__ bv0,
    const float* __restrict__ Wv1, const float* __restrict__ bv1,
    const float* __restrict__ Wv2, const float* __restrict__ bv2,
    const float* __restrict__ Wa0, const float* __restrict__ ba0,
    const float* __restrict__ Wa1, const float* __restrict__ ba1,
    float* __restrict__ ws)
{
    __shared__ __align__(16) u16 Wa1s[128*136];
    __shared__ __align__(16) u16 Wsel[128*72];
    __shared__ __align__(16) u16 inrows[16*72];
    __shared__ __align__(16) float P[16*132];
    const int t = threadIdx.x;

    if (blockIdx.x < 256) {
        // ---------------- PO / Y tile ----------------
        const int b = blockIdx.x >> 5;
        const int r0 = (blockIdx.x & 31) * 16;
        const int side = (r0 >= 256) ? 1 : 0;

        {
            const u16* wa1b = (const u16*)(ws + FB + WA1B);
            #pragma unroll
            for (int k = 0; k < 8; ++k) {
                const int e4 = t + k*256;
                const int g = e4 >> 4, hq = (e4 & 15) * 8;
                *(uint4*)&Wa1s[g*136 + hq] = *(const uint4*)(wa1b + g*128 + hq);
            }
        }
        {
            const u16* wsb = (const u16*)(ws + FB + (side ? WIB : WOB));
            #pragma unroll
            for (int k = 0; k < 4; ++k) {
                const int e4 = t + k*256;
                const int h = e4 >> 3, dq = (e4 & 7) * 8;
                *(uint4*)&Wsel[h*72 + dq] = *(const uint4*)(wsb + h*64 + dq);
            }
        }
        {
            const int r = t >> 4, dq = (t & 15) * 4;
            const float* src = side
                ? (ins + b*16384 + (r0 - 256 + r)*64 + dq)
                : (ope + b*16512 + (1 + r0 + r)*64 + dq);
            const float4 w = *(const float4*)src;
            ushort4 u; u.x = f2b(w.x); u.y = f2b(w.y); u.z = f2b(w.z); u.w = f2b(w.w);
            *(ushort4*)&inrows[r*72 + dq] = u;
        }
        __syncthreads();

        const int r = t >> 4;
        const int q = t & 15;

        // P[r][h] = inrow[r] . Wsel[h]
        {
            float acc[8] = {0.f,0.f,0.f,0.f,0.f,0.f,0.f,0.f};
            #pragma unroll
            for (int d8 = 0; d8 < 64; d8 += 8) {
                float iv[8];
                cvt8(*(const uint4*)&inrows[r*72 + d8], iv);
                #pragma unroll
                for (int k = 0; k < 8; ++k) {
                    float wv[8];
                    cvt8(*(const uint4*)&Wsel[(q + 16*k)*72 + d8], wv);
                    #pragma unroll
                    for (int j = 0; j < 8; ++j) acc[k] += wv[j] * iv[j];
                }
            }
            #pragma unroll
            for (int k = 0; k < 8; ++k) P[r*132 + q + 16*k] = acc[k];
        }
        __syncthreads();

        // out[r][g] = P[r] . Wa1[g]; C-reduce over g
        {
            float acc[8] = {0.f,0.f,0.f,0.f,0.f,0.f,0.f,0.f};
            #pragma unroll
            for (int h8 = 0; h8 < 128; h8 += 8) {
                const float4 p0 = *(const float4*)&P[r*132 + h8];
                const float4 p1 = *(const float4*)&P[r*132 + h8 + 4];
                #pragma unroll
                for (int k = 0; k < 8; ++k) {
                    float wv[8];
                    cvt8(*(const uint4*)&Wa1s[(q + 16*k)*136 + h8], wv);
                    float a = acc[k];
                    a += wv[0]*p0.x + wv[1]*p0.y + wv[2]*p0.z + wv[3]*p0.w;
                    a += wv[4]*p1.x + wv[5]*p1.y + wv[6]*p1.z + wv[7]*p1.w;
                    acc[k] = a;
                }
            }
            float part = 0.f;
            const int row = side ? (b*256 + r0 - 256 + r) : (b*256 + r0 + r);
            float* dst = side ? (ws + 262144 + row*128) : (ws + row*128);
            #pragma unroll
            for (int k = 0; k < 8; ++k) {
                const int g = q + 16*k;
                part = fmaf(ws[FB + 1024 + g], acc[k], part);   // wa' * val
                dst[g] = acc[k];
            }
            part += __shfl_xor(part, 1);
            part += __shfl_xor(part, 2);
            part += __shfl_xor(part, 4);
            part += __shfl_xor(part, 8);
            if (q == 0) {
                if (!side) ws[FB + 2320 + row] = part;          // C1PO
                else       ws[FB + 4368 + row] = part;          // C2
            }
        }
    } else {
        // ---------------- LSTM + V head + S + C1S (block b) ----------------
        const int b = blockIdx.x - 256;
        float* f = (float*)Wa1s;     // alias LDS
        float* state = f;            // 64
        float* hvec  = f + 64;       // 64
        float* gl    = f + 128;      // 256
        float* hn_s  = f + 384;      // 64
        float* t0a   = f + 448;      // 128
        float* t1a   = f + 576;      // 128
        float* s2s   = f + 704;      // 128
        float* red   = f + 832;      // 256

        if (t < 64) {
            float s = 0.f;
            #pragma unroll
            for (int s8 = 0; s8 < 8; ++s8) s += ws[FB + PART + (b*8 + s8)*64 + t];
            state[t] = s * (1.f/256.f);
        } else if (t < 128) hvec[t-64] = hin[b*64 + (t-64)];
        __syncthreads();

        {
            float g = b_ih[t] + b_hh[t];
            const float4* wi = (const float4*)(W_ih + t*64);
            const float4* wh = (const float4*)(W_hh + t*64);
            #pragma unroll
            for (int k = 0; k < 16; ++k)
                g += dot4(wi[k], *(const float4*)&state[k*4])
                   + dot4(wh[k], *(const float4*)&hvec[k*4]);
            gl[t] = g;
        }
        __syncthreads();

        if (t < 64) {
            const float ig = gl[t], fg = gl[64+t], gg = gl[128+t], og = gl[192+t];
            const float c  = cin[b*64 + t];
            const float si = 1.f/(1.f + expf(-ig));
            const float sf = 1.f/(1.f + expf(-fg));
            const float so = 1.f/(1.f + expf(-og));
            const float cn = sf*c + si*tanhf(gg);
            const float hn = so*tanhf(cn);
            ws[FB + 1288 + b*64 + t] = hn;
            ws[FB + 1800 + b*64 + t] = cn;
            hn_s[t] = hn;
        }
        __syncthreads();

        if (t < 128) {
            float a = bv0[t];
            const float4* w = (const float4*)(Wv0 + t*64);
            #pragma unroll
            for (int k = 0; k < 16; ++k) a += dot4(w[k], *(const float4*)&hn_s[k*4]);
            t0a[t] = a;
        }
        __syncthreads();
        if (t < 128) {
            float a = bv1[t];
            const float4* w = (const float4*)(Wv1 + t*128);
            #pragma unroll
            for (int k = 0; k < 32; ++k) a += dot4(w[k], *(const float4*)&t0a[k*4]);
            a = (a >= 0.f) ? a : 0.01f*a;
            t1a[t] = a * Wv2[t];
            float s2 = ba0[t];
            const float4* w0 = (const float4*)(Wa0 + t*192);
            #pragma unroll
            for (int k = 0; k < 16; ++k) s2 += dot4(w0[k], *(const float4*)&hn_s[k*4]);
            s2s[t] = s2;
        }
        __syncthreads();
        if (t < 128) {
            // S[b][g] = s2 . Wa1[g] + ba1[g]   (fp32 Wa1)
            float sv = ba1[t];
            const float4* w = (const float4*)(Wa1 + t*128);
            #pragma unroll
            for (int k = 0; k < 32; ++k) sv += dot4(w[k], *(const float4*)&s2s[k*4]);
            ws[FB + SOFF + b*128 + t] = sv;
            red[t] = ws[FB + 1024 + t] * sv;        // wa' * S
        }
        __syncthreads();
        if (t < 64) {
            float c = red[t] + red[t + 64];
            float v = t1a[t] + t1a[t + 64];
            c += __shfl_xor(c, 32); v += __shfl_xor(v, 32);
            c += __shfl_xor(c, 16); v += __shfl_xor(v, 16);
            c += __shfl_xor(c, 8);  v += __shfl_xor(v, 8);
            c += __shfl_xor(c, 4);  v += __shfl_xor(v, 4);
            c += __shfl_xor(c, 2);  v += __shfl_xor(v, 2);
            c += __shfl_xor(c, 1);  v += __shfl_xor(v, 1);
            if (t == 0) {
                ws[FB + C1S + b]  = c + ws[FB + 2313];   // + ba2
                ws[FB + 1280 + b] = v + bv2[0];          // V
            }
        }
    }
}

// ============================================================================
// K3: A[b][o][i] = C1PO[b,o] + C1S[b] + C2[b,i] + sum_g wb'[g]*|PO + S + Y|.
// grid(512), block(256). Block 0 emits V/hn/cn last.
// ============================================================================
__global__ __launch_bounds__(256) void k3_adv(const float* __restrict__ ws,
                                              float* __restrict__ out)
{
    const int t = threadIdx.x;
    const int b = blockIdx.x >> 6;
    const int o0 = (blockIdx.x & 63) * 4;
    const float* wb = ws + FB + 1152;

    float acc[4] = {0.f, 0.f, 0.f, 0.f};
    #pragma unroll
    for (int gc = 0; gc < 8; ++gc) {              // 16 g per chunk
        float syv[16], wv[16];
        {
            const float* yr = ws + 262144 + (b*256 + t)*128 + gc*16;
            const float* sr = ws + FB + SOFF + b*128 + gc*16;   // uniform
            #pragma unroll
            for (int k = 0; k < 4; ++k) {
                const float4 y4 = *(const float4*)(yr + k*4);
                const float4 s4 = *(const float4*)(sr + k*4);
                syv[k*4+0] = y4.x + s4.x; syv[k*4+1] = y4.y + s4.y;
                syv[k*4+2] = y4.z + s4.z; syv[k*4+3] = y4.w + s4.w;
                *(float4*)&wv[k*4] = *(const float4*)(wb + gc*16 + k*4);
            }
        }
        #pragma unroll
        for (int o = 0; o < 4; ++o) {
            const float* xr = ws + (b*256 + o0 + o)*128 + gc*16;   // uniform
            float a = acc[o];
            #pragma unroll
            for (int k = 0; k < 4; ++k) {
                const float4 x4 = *(const float4*)(xr + k*4);
                a = fmaf(wv[k*4+0], fabsf(x4.x + syv[k*4+0]), a);
                a = fmaf(wv[k*4+1], fabsf(x4.y + syv[k*4+1]), a);
                a = fmaf(wv[k*4+2], fabsf(x4.z + syv[k*4+2]), a);
                a = fmaf(wv[k*4+3], fabsf(x4.w + syv[k*4+3]), a);
            }
            acc[o] = a;
        }
    }
    const float c2  = ws[FB + 4368 + b*256 + t];
    const float c1s = ws[FB + C1S + b];
    #pragma unroll
    for (int o = 0; o < 4; ++o)
        out[8 + b*65536 + (o0 + o)*256 + t] =
            ws[FB + 2320 + b*256 + o0 + o] + c1s + c2 + acc[o];

    if (blockIdx.x == 0) {
        if (t < 8) out[t] = ws[FB + 1280 + t];              // V fp32
        #pragma unroll
        for (int j = t; j < 512; j += 256) {
            out[524296 + j] = ws[FB + 1288 + j];            // hn fp32
            out[524808 + j] = ws[FB + 1800 + j];            // cn fp32
        }
    }
}

// ============================================================================
extern "C" void kernel_launch(void* const* d_in, const int* in_sizes, int n_in,
                              void* d_out, int out_size, void* d_ws, size_t ws_size,
                              hipStream_t stream) {
    float* ws = (float*)d_ws;
    float* out = (float*)d_out;                 // output is fp32

    const float* ope = (const float*)d_in[0];
    const float* ins = (const float*)d_in[1];

    k0_pre  <<<dim3(81),  dim3(256), 0, stream>>>(
        ope, (const float*)d_in[14], (const float*)d_in[16],
        (const float*)d_in[18], (const float*)d_in[19], ws);
    k12_main<<<dim3(264), dim3(256), 0, stream>>>(
        ope, ins,
        (const float*)d_in[2], (const float*)d_in[3],
        (const float*)d_in[4], (const float*)d_in[5],
        (const float*)d_in[6], (const float*)d_in[7],
        (const float*)d_in[8], (const float*)d_in[9],
        (const float*)d_in[10], (const float*)d_in[11],
        (const float*)d_in[12], (const float*)d_in[13],
        (const float*)d_in[14], (const float*)d_in[15],
        (const float*)d_in[16], (const float*)d_in[17], ws);
    k3_adv  <<<dim3(512), dim3(256), 0, stream>>>(ws, out);
}

// Round 10
// 122.760 us; speedup vs baseline: 1.1147x; 1.0037x over previous
//
#include <hip/hip_runtime.h>
#include <hip/hip_bf16.h>
#include <math.h>

typedef unsigned short u16;

// ---- ws layout (float offsets), FB = 524288 ----
// [0, 262144)        : PO[b][o][g] fp32
// [262144, 524288)   : Y[b][i][g] fp32
// FB+1280 .. +1288   : V fp32                  (k12 LSTM blocks)
// FB+1288 .. +1800   : hn fp32
// FB+1800 .. +2312   : cn fp32
// FB+2320 .. +4368   : C1PO[b][o] = sum_g wa'*PO
// FB+4368 .. +6416   : C2[b][i]   = sum_g wa'*Y
// FB+26896.. +27920  : S[b][g] = s2.Wa1 + ba1
// FB+27920.. +27928  : C1S[b] = sum_g wa'*S + ba2
#define FB    524288
#define SOFF  26896
#define C1S   27920

__device__ __forceinline__ u16 f2b(float x) { __hip_bfloat16 b = __float2bfloat16(x); return *(u16*)&b; }
__device__ __forceinline__ void cvt8(const uint4 u, float* f) {
    f[0] = __uint_as_float(u.x << 16); f[1] = __uint_as_float(u.x & 0xFFFF0000u);
    f[2] = __uint_as_float(u.y << 16); f[3] = __uint_as_float(u.y & 0xFFFF0000u);
    f[4] = __uint_as_float(u.z << 16); f[5] = __uint_as_float(u.z & 0xFFFF0000u);
    f[6] = __uint_as_float(u.w << 16); f[7] = __uint_as_float(u.w & 0xFFFF0000u);
}
__device__ __forceinline__ float dot4(const float4 a, const float4 b) {
    return a.x*b.x + a.y*b.y + a.z*b.z + a.w*b.w;
}

// ============================================================================
// K12: blocks 0..255 = PO/Y tiles (+C1PO/C2 reduces, self-staged weights);
//      blocks 256..263 = mean + LSTM + V head + S[b][g] + C1S[b].
// grid(264), block(256). Depends only on inputs.
// ============================================================================
__global__ __launch_bounds__(256) void k12_main(
    const float* __restrict__ ope, const float* __restrict__ ins,
    const float* __restrict__ hin, const float* __restrict__ cin,
    const float* __restrict__ W_ih, const float* __restrict__ W_hh,
    const float* __restrict__ b_ih, const float* __restrict__ b_hh,
    const float* __restrict__ Wv0, const float* __restrict__ bv0,
    const float* __restrict__ Wv1, const float* __restrict__ bv1,
    const float* __restrict__ Wv2, const float* __restrict__ bv2,
    const float* __restrict__ Wa0, const float* __restrict__ ba0,
    const float* __restrict__ Wa1, const float* __restrict__ ba1,
    const float* __restrict__ Wa2, const float* __restrict__ ba2,
    float* __restrict__ ws)
{
    __shared__ __align__(16) u16 Wa1s[128*136];
    __shared__ __align__(16) u16 Wsel[128*72];
    __shared__ __align__(16) u16 inrows[16*72];
    __shared__ __align__(16) float P[16*132];
    const int t = threadIdx.x;

    if (blockIdx.x < 256) {
        // ---------------- PO / Y tile ----------------
        const int b = blockIdx.x >> 5;
        const int r0 = (blockIdx.x & 31) * 16;
        const int side = (r0 >= 256) ? 1 : 0;

        // stage Wa1 fp32 -> LDS bf16 [128][136]
        #pragma unroll
        for (int k = 0; k < 16; ++k) {
            const int e4 = t + k*256;
            const int g = e4 >> 5, hq = (e4 & 31) * 4;
            const float4 w = *(const float4*)(Wa1 + g*128 + hq);
            ushort4 u; u.x = f2b(w.x); u.y = f2b(w.y); u.z = f2b(w.z); u.w = f2b(w.w);
            *(ushort4*)&Wa1s[g*136 + hq] = u;
        }
        // stage Wo/Wi fp32 -> LDS bf16 [128][72]
        #pragma unroll
        for (int k = 0; k < 8; ++k) {
            const int e4 = t + k*256;
            const int h = e4 >> 4, dq = (e4 & 15) * 4;
            const float4 w = *(const float4*)(Wa0 + h*192 + 64 + side*64 + dq);
            ushort4 u; u.x = f2b(w.x); u.y = f2b(w.y); u.z = f2b(w.z); u.w = f2b(w.w);
            *(ushort4*)&Wsel[h*72 + dq] = u;
        }
        // stage 16 input rows -> LDS bf16 [16][72]
        {
            const int r = t >> 4, dq = (t & 15) * 4;
            const float* src = side
                ? (ins + b*16384 + (r0 - 256 + r)*64 + dq)
                : (ope + b*16512 + (1 + r0 + r)*64 + dq);
            const float4 w = *(const float4*)src;
            ushort4 u; u.x = f2b(w.x); u.y = f2b(w.y); u.z = f2b(w.z); u.w = f2b(w.w);
            *(ushort4*)&inrows[r*72 + dq] = u;
        }
        __syncthreads();

        const int r = t >> 4;
        const int q = t & 15;

        // P[r][h] = inrow[r] . Wsel[h]
        {
            float acc[8] = {0.f,0.f,0.f,0.f,0.f,0.f,0.f,0.f};
            #pragma unroll
            for (int d8 = 0; d8 < 64; d8 += 8) {
                float iv[8];
                cvt8(*(const uint4*)&inrows[r*72 + d8], iv);
                #pragma unroll
                for (int k = 0; k < 8; ++k) {
                    float wv[8];
                    cvt8(*(const uint4*)&Wsel[(q + 16*k)*72 + d8], wv);
                    #pragma unroll
                    for (int j = 0; j < 8; ++j) acc[k] += wv[j] * iv[j];
                }
            }
            #pragma unroll
            for (int k = 0; k < 8; ++k) P[r*132 + q + 16*k] = acc[k];
        }
        __syncthreads();

        // out[r][g] = P[r] . Wa1[g]; C-reduce over g with wa' = 0.505*Wa2
        {
            float acc[8] = {0.f,0.f,0.f,0.f,0.f,0.f,0.f,0.f};
            #pragma unroll
            for (int h8 = 0; h8 < 128; h8 += 8) {
                const float4 p0 = *(const float4*)&P[r*132 + h8];
                const float4 p1 = *(const float4*)&P[r*132 + h8 + 4];
                #pragma unroll
                for (int k = 0; k < 8; ++k) {
                    float wv[8];
                    cvt8(*(const uint4*)&Wa1s[(q + 16*k)*136 + h8], wv);
                    float a = acc[k];
                    a += wv[0]*p0.x + wv[1]*p0.y + wv[2]*p0.z + wv[3]*p0.w;
                    a += wv[4]*p1.x + wv[5]*p1.y + wv[6]*p1.z + wv[7]*p1.w;
                    acc[k] = a;
                }
            }
            float part = 0.f;
            const int row = side ? (b*256 + r0 - 256 + r) : (b*256 + r0 + r);
            float* dst = side ? (ws + 262144 + row*128) : (ws + row*128);
            #pragma unroll
            for (int k = 0; k < 8; ++k) {
                const int g = q + 16*k;
                part = fmaf(0.505f * Wa2[g], acc[k], part);
                dst[g] = acc[k];
            }
            part += __shfl_xor(part, 1);
            part += __shfl_xor(part, 2);
            part += __shfl_xor(part, 4);
            part += __shfl_xor(part, 8);
            if (q == 0) {
                if (!side) ws[FB + 2320 + row] = part;          // C1PO
                else       ws[FB + 4368 + row] = part;          // C2
            }
        }
    } else {
        // ---------------- mean + LSTM + V head + S + C1S (block b) ----------
        const int b = blockIdx.x - 256;
        float* f = (float*)Wa1s;     // alias LDS
        float* state = f;            // 64
        float* hvec  = f + 64;       // 64
        float* gl    = f + 128;      // 256
        float* hn_s  = f + 384;      // 64
        float* t0a   = f + 448;      // 128
        float* t1a   = f + 576;      // 128
        float* s2s   = f + 704;      // 128
        float* red   = f + 832;      // 256

        // mean over rows 1..256 of ope[b], directly (hidden under PO blocks)
        {
            const int d = t & 63, q = t >> 6;
            const float* p = ope + b*16512 + (1 + q*64)*64 + d;
            float s = 0.f;
            #pragma unroll 8
            for (int r = 0; r < 64; ++r) s += p[r*64];
            red[t] = s;
        }
        __syncthreads();
        if (t < 64)       state[t]   = (red[t] + red[t+64] + red[t+128] + red[t+192]) * (1.f/256.f);
        else if (t < 128) hvec[t-64] = hin[b*64 + (t-64)];
        __syncthreads();

        {
            float g = b_ih[t] + b_hh[t];
            const float4* wi = (const float4*)(W_ih + t*64);
            const float4* wh = (const float4*)(W_hh + t*64);
            #pragma unroll
            for (int k = 0; k < 16; ++k)
                g += dot4(wi[k], *(const float4*)&state[k*4])
                   + dot4(wh[k], *(const float4*)&hvec[k*4]);
            gl[t] = g;
        }
        __syncthreads();

        if (t < 64) {
            const float ig = gl[t], fg = gl[64+t], gg = gl[128+t], og = gl[192+t];
            const float c  = cin[b*64 + t];
            const float si = 1.f/(1.f + expf(-ig));
            const float sf = 1.f/(1.f + expf(-fg));
            const float so = 1.f/(1.f + expf(-og));
            const float cn = sf*c + si*tanhf(gg);
            const float hn = so*tanhf(cn);
            ws[FB + 1288 + b*64 + t] = hn;
            ws[FB + 1800 + b*64 + t] = cn;
            hn_s[t] = hn;
        }
        __syncthreads();

        if (t < 128) {
            float a = bv0[t];
            const float4* w = (const float4*)(Wv0 + t*64);
            #pragma unroll
            for (int k = 0; k < 16; ++k) a += dot4(w[k], *(const float4*)&hn_s[k*4]);
            t0a[t] = a;
        }
        __syncthreads();
        if (t < 128) {
            float a = bv1[t];
            const float4* w = (const float4*)(Wv1 + t*128);
            #pragma unroll
            for (int k = 0; k < 32; ++k) a += dot4(w[k], *(const float4*)&t0a[k*4]);
            a = (a >= 0.f) ? a : 0.01f*a;
            t1a[t] = a * Wv2[t];
            float s2 = ba0[t];
            const float4* w0 = (const float4*)(Wa0 + t*192);
            #pragma unroll
            for (int k = 0; k < 16; ++k) s2 += dot4(w0[k], *(const float4*)&hn_s[k*4]);
            s2s[t] = s2;
        }
        __syncthreads();
        if (t < 128) {
            // S[b][g] = s2 . Wa1[g] + ba1[g]   (fp32 Wa1)
            float sv = ba1[t];
            const float4* w = (const float4*)(Wa1 + t*128);
            #pragma unroll
            for (int k = 0; k < 32; ++k) sv += dot4(w[k], *(const float4*)&s2s[k*4]);
            ws[FB + SOFF + b*128 + t] = sv;
            red[t] = 0.505f * Wa2[t] * sv;          // wa' * S
        }
        __syncthreads();
        if (t < 64) {
            float c = red[t] + red[t + 64];
            float v = t1a[t] + t1a[t + 64];
            c += __shfl_xor(c, 32); v += __shfl_xor(v, 32);
            c += __shfl_xor(c, 16); v += __shfl_xor(v, 16);
            c += __shfl_xor(c, 8);  v += __shfl_xor(v, 8);
            c += __shfl_xor(c, 4);  v += __shfl_xor(v, 4);
            c += __shfl_xor(c, 2);  v += __shfl_xor(v, 2);
            c += __shfl_xor(c, 1);  v += __shfl_xor(v, 1);
            if (t == 0) {
                ws[FB + C1S + b]  = c + ba2[0];
                ws[FB + 1280 + b] = v + bv2[0];
            }
        }
    }
}

// ============================================================================
// K3: A[b][o][i] = C1PO[b,o] + C1S[b] + C2[b,i] + sum_g wb'[g]*|PO + S + Y|,
// wb' = 0.495*Wa2. grid(512), block(256). Block 0 emits V/hn/cn last.
// ============================================================================
__global__ __launch_bounds__(256) void k3_adv(const float* __restrict__ ws,
                                              const float* __restrict__ Wa2,
                                              float* __restrict__ out)
{
    const int t = threadIdx.x;
    const int b = blockIdx.x >> 6;
    const int o0 = (blockIdx.x & 63) * 4;

    float acc[4] = {0.f, 0.f, 0.f, 0.f};
    #pragma unroll
    for (int gc = 0; gc < 8; ++gc) {              // 16 g per chunk
        float syv[16], wv[16];
        {
            const float* yr = ws + 262144 + (b*256 + t)*128 + gc*16;
            const float* sr = ws + FB + SOFF + b*128 + gc*16;    // uniform
            const float* wr = Wa2 + gc*16;                       // uniform
            #pragma unroll
            for (int k = 0; k < 4; ++k) {
                const float4 y4 = *(const float4*)(yr + k*4);
                const float4 s4 = *(const float4*)(sr + k*4);
                const float4 w4 = *(const float4*)(wr + k*4);
                syv[k*4+0] = y4.x + s4.x; syv[k*4+1] = y4.y + s4.y;
                syv[k*4+2] = y4.z + s4.z; syv[k*4+3] = y4.w + s4.w;
                wv[k*4+0] = 0.495f*w4.x; wv[k*4+1] = 0.495f*w4.y;
                wv[k*4+2] = 0.495f*w4.z; wv[k*4+3] = 0.495f*w4.w;
            }
        }
        #pragma unroll
        for (int o = 0; o < 4; ++o) {
            const float* xr = ws + (b*256 + o0 + o)*128 + gc*16;   // uniform
            float a = acc[o];
            #pragma unroll
            for (int k = 0; k < 4; ++k) {
                const float4 x4 = *(const float4*)(xr + k*4);
                a = fmaf(wv[k*4+0], fabsf(x4.x + syv[k*4+0]), a);
                a = fmaf(wv[k*4+1], fabsf(x4.y + syv[k*4+1]), a);
                a = fmaf(wv[k*4+2], fabsf(x4.z + syv[k*4+2]), a);
                a = fmaf(wv[k*4+3], fabsf(x4.w + syv[k*4+3]), a);
            }
            acc[o] = a;
        }
    }
    const float c2  = ws[FB + 4368 + b*256 + t];
    const float c1s = ws[FB + C1S + b];
    #pragma unroll
    for (int o = 0; o < 4; ++o)
        out[8 + b*65536 + (o0 + o)*256 + t] =
            ws[FB + 2320 + b*256 + o0 + o] + c1s + c2 + acc[o];

    if (blockIdx.x == 0) {
        if (t < 8) out[t] = ws[FB + 1280 + t];              // V fp32
        #pragma unroll
        for (int j = t; j < 512; j += 256) {
            out[524296 + j] = ws[FB + 1288 + j];            // hn fp32
            out[524808 + j] = ws[FB + 1800 + j];            // cn fp32
        }
    }
}

// ============================================================================
extern "C" void kernel_launch(void* const* d_in, const int* in_sizes, int n_in,
                              void* d_out, int out_size, void* d_ws, size_t ws_size,
                              hipStream_t stream) {
    float* ws = (float*)d_ws;
    float* out = (float*)d_out;                 // output is fp32

    k12_main<<<dim3(264), dim3(256), 0, stream>>>(
        (const float*)d_in[0], (const float*)d_in[1],
        (const float*)d_in[2], (const float*)d_in[3],
        (const float*)d_in[4], (const float*)d_in[5],
        (const float*)d_in[6], (const float*)d_in[7],
        (const float*)d_in[8], (const float*)d_in[9],
        (const float*)d_in[10], (const float*)d_in[11],
        (const float*)d_in[12], (const float*)d_in[13],
        (const float*)d_in[14], (const float*)d_in[15],
        (const float*)d_in[16], (const float*)d_in[17],
        (const float*)d_in[18], (const float*)d_in[19], ws);
    k3_adv  <<<dim3(512), dim3(256), 0, stream>>>(ws, (const float*)d_in[18], out);
}